// Round 3
// baseline (3144.387 us; speedup 1.0000x reference)
//
#include <hip/hip_runtime.h>
#include <hip/hip_bf16.h>
#include <math.h>

// ---- problem constants ----
constexpr int C_HID  = 3072;
constexpr int C_L    = 2048;
constexpr int C_NH   = 24;
constexpr int C_HD   = 128;
constexpr int C_MLP  = 12288;
constexpr int C_N1   = 21504;   // 3*HID + MLP
constexpr int C_K2   = 15360;   // HID + MLP

typedef __attribute__((ext_vector_type(8))) short bf16x8;   // 8 bf16 (4 VGPRs) - proven type for gfx950 mfma builtins
typedef __attribute__((ext_vector_type(4))) float f32x4;
typedef __attribute__((ext_vector_type(4))) unsigned short us4;
typedef __attribute__((ext_vector_type(8))) unsigned short us8;

__device__ __forceinline__ unsigned short f2bf(float f) {
  unsigned u = __builtin_bit_cast(unsigned, f);
  u += 0x7FFFu + ((u >> 16) & 1u);          // RNE
  return (unsigned short)(u >> 16);
}
__device__ __forceinline__ float bf2f(unsigned short h) {
  unsigned u = ((unsigned)h) << 16;
  return __builtin_bit_cast(float, u);
}

// ---------------- mod = silu(vec) @ mod_w + mod_b ----------------
__global__ void k_silu_gemv(const float* __restrict__ vec, const float* __restrict__ mod_w,
                            float* __restrict__ partial) {
  __shared__ float sv[192];
  int tid = threadIdx.x;
  int ib = blockIdx.y;
  if (tid < 192) {
    float v = vec[ib * 192 + tid];
    sv[tid] = v / (1.f + __expf(-v));
  }
  __syncthreads();
  int j = blockIdx.x * 256 + tid;
  const float* wp = mod_w + (size_t)(ib * 192) * 9216 + j;
  float acc = 0.f;
#pragma unroll 4
  for (int r = 0; r < 192; ++r) acc += sv[r] * wp[(size_t)r * 9216];
  partial[ib * 9216 + j] = acc;
}

__global__ void k_reduce_mod(const float* __restrict__ partial, const float* __restrict__ mod_b,
                             float* __restrict__ modv) {
  int j = blockIdx.x * 256 + threadIdx.x;
  float a = mod_b[j];
#pragma unroll
  for (int i = 0; i < 16; ++i) a += partial[i * 9216 + j];
  modv[j] = a;
}

// ---------------- x_mod = (1+scale)*LN(x) + shift  -> bf16 ----------------
__global__ void k_ln_mod(const float* __restrict__ x, const float* __restrict__ modv,
                         unsigned short* __restrict__ xmod) {
  __shared__ float red[8];
  int t = blockIdx.x, tid = threadIdx.x;
  const float4* xr = (const float4*)(x + (size_t)t * C_HID);
  float4 v[3];
  float s = 0.f, sq = 0.f;
#pragma unroll
  for (int i = 0; i < 3; ++i) {
    v[i] = xr[tid + i * 256];
    s  += v[i].x + v[i].y + v[i].z + v[i].w;
    sq += v[i].x * v[i].x + v[i].y * v[i].y + v[i].z * v[i].z + v[i].w * v[i].w;
  }
#pragma unroll
  for (int off = 32; off; off >>= 1) { s += __shfl_xor(s, off); sq += __shfl_xor(sq, off); }
  int wid = tid >> 6;
  if ((tid & 63) == 0) { red[wid] = s; red[4 + wid] = sq; }
  __syncthreads();
  s  = red[0] + red[1] + red[2] + red[3];
  sq = red[4] + red[5] + red[6] + red[7];
  float mu  = s * (1.f / 3072.f);
  float var = sq * (1.f / 3072.f) - mu * mu;
  float rs  = rsqrtf(var + 1e-6f);
#pragma unroll
  for (int i = 0; i < 3; ++i) {
    int c0 = (tid + i * 256) * 4;
    float4 sh = *(const float4*)(modv + c0);
    float4 sc = *(const float4*)(modv + 3072 + c0);
    const float* vv = (const float*)&v[i];
    us4 o;
    o[0] = f2bf((vv[0] - mu) * rs * (1.f + sc.x) + sh.x);
    o[1] = f2bf((vv[1] - mu) * rs * (1.f + sc.y) + sh.y);
    o[2] = f2bf((vv[2] - mu) * rs * (1.f + sc.z) + sh.z);
    o[3] = f2bf((vv[3] - mu) * rs * (1.f + sc.w) + sh.w);
    *(us4*)(xmod + (size_t)t * C_HID + c0) = o;
  }
}

// ---------------- GEMM: C[M,N] = A[M,K](bf16) * B[K,N](fp32->bf16) + bias ----------------
// 128x128 tile, BK=64, 4 waves (2x2 of 64x64). LDS XOR slot-swizzle (T2).
// EPI=0: out bf16. EPI=1: out = resid + gate*(acc+bias), fp32.
template<int EPI>
__global__ __launch_bounds__(256, 2)
void k_gemm(const unsigned short* __restrict__ A, const float* __restrict__ B,
            const float* __restrict__ bias,
            unsigned short* __restrict__ outb, float* __restrict__ outf,
            const float* __restrict__ resid, const float* __restrict__ gate,
            int M, int N, int K, int tiles_m) {
  __shared__ unsigned short As[128 * 64];
  __shared__ unsigned short Bs[128 * 64];
  int bid = blockIdx.x;
  int nt = bid / tiles_m, mt = bid % tiles_m;
  int n0 = nt * 128, m0 = mt * 128;
  int tid = threadIdx.x, l = tid & 63, wid = tid >> 6;
  int wr = wid >> 1, wc = wid & 1;
  int la = l & 15, lk = l >> 4;
  f32x4 acc[4][4] = {};

  int bkq = tid >> 4;           // 0..15 -> k rows bkq*4..+4
  int bnc = (tid & 15) * 8;     // 8 cols
  int bkbase = bkq * 4;

  for (int k0 = 0; k0 < K; k0 += 64) {
    // stage A: 128x64 bf16, swizzled 16B slots
#pragma unroll
    for (int it = 0; it < 4; ++it) {
      int c = it * 256 + tid;
      int row = c >> 3, sslot = c & 7;
      bf16x8 vA = *(const bf16x8*)(A + (size_t)(m0 + row) * K + k0 + sslot * 8);
      *(bf16x8*)((char*)As + row * 128 + ((sslot ^ (row & 7)) * 16)) = vA;
    }
    // stage B: w[k0..k0+64][n0..n0+128] fp32 -> Bs[n][k] bf16 (transposed), swizzled
    {
      const float* bp = B + (size_t)(k0 + bkbase) * N + n0 + bnc;
      float fv[4][8];
#pragma unroll
      for (int r = 0; r < 4; ++r) {
        float4 a = *(const float4*)(bp + (size_t)r * N);
        float4 b = *(const float4*)(bp + (size_t)r * N + 4);
        fv[r][0] = a.x; fv[r][1] = a.y; fv[r][2] = a.z; fv[r][3] = a.w;
        fv[r][4] = b.x; fv[r][5] = b.y; fv[r][6] = b.z; fv[r][7] = b.w;
      }
#pragma unroll
      for (int j = 0; j < 8; ++j) {
        int n = bnc + j;
        us4 w;
        w[0] = f2bf(fv[0][j]); w[1] = f2bf(fv[1][j]);
        w[2] = f2bf(fv[2][j]); w[3] = f2bf(fv[3][j]);
        int slot = (bkq >> 1) ^ (n & 7);
        *(us4*)((char*)Bs + n * 128 + slot * 16 + (bkbase & 7) * 2) = w;
      }
    }
    __syncthreads();
#pragma unroll
    for (int kc = 0; kc < 2; ++kc) {
      bf16x8 af[4], bfr[4];
      int sa = kc * 4 + lk;
#pragma unroll
      for (int mi = 0; mi < 4; ++mi) {
        int row = wr * 64 + mi * 16 + la;
        af[mi] = *(const bf16x8*)((char*)As + row * 128 + ((sa ^ (row & 7)) * 16));
      }
#pragma unroll
      for (int ni = 0; ni < 4; ++ni) {
        int row = wc * 64 + ni * 16 + la;
        bfr[ni] = *(const bf16x8*)((char*)Bs + row * 128 + ((sa ^ (row & 7)) * 16));
      }
#pragma unroll
      for (int mi = 0; mi < 4; ++mi)
#pragma unroll
        for (int ni = 0; ni < 4; ++ni)
          acc[mi][ni] = __builtin_amdgcn_mfma_f32_16x16x32_bf16(af[mi], bfr[ni], acc[mi][ni], 0, 0, 0);
    }
    __syncthreads();
  }
  // epilogue
#pragma unroll
  for (int mi = 0; mi < 4; ++mi) {
#pragma unroll
    for (int ni = 0; ni < 4; ++ni) {
      int col = n0 + wc * 64 + ni * 16 + la;
      float bv = bias[col];
#pragma unroll
      for (int j = 0; j < 4; ++j) {
        int row = m0 + wr * 64 + mi * 16 + lk * 4 + j;
        float v = acc[mi][ni][j] + bv;
        if (EPI == 0) {
          outb[(size_t)row * N + col] = f2bf(v);
        } else {
          outf[(size_t)row * N + col] = resid[(size_t)row * N + col] + gate[col] * v;
        }
      }
    }
  }
}

// ---------------- qkv post: rmsnorm(q,k) + rope, rearrange to [head][t][d] ----------------
__global__ void k_qkv_post(const unsigned short* __restrict__ h, const float* __restrict__ pe,
                           const float* __restrict__ qw, const float* __restrict__ kw,
                           unsigned short* __restrict__ qb, unsigned short* __restrict__ kb,
                           unsigned short* __restrict__ vb) {
  int wid = threadIdx.x >> 6, l = threadIdx.x & 63;
  int p = blockIdx.x * 4 + wid;
  int t = p / 24, head = p % 24;
  const unsigned short* hr = h + (size_t)t * C_N1 + head * C_HD;
  unsigned q2 = *(const unsigned*)(hr + 2 * l);
  unsigned k2 = *(const unsigned*)(hr + 3072 + 2 * l);
  unsigned v2 = *(const unsigned*)(hr + 6144 + 2 * l);
  float q0 = bf2f((unsigned short)q2), q1 = bf2f((unsigned short)(q2 >> 16));
  float k0 = bf2f((unsigned short)k2), k1 = bf2f((unsigned short)(k2 >> 16));
  float sq = q0 * q0 + q1 * q1;
  float sk = k0 * k0 + k1 * k1;
#pragma unroll
  for (int off = 32; off; off >>= 1) { sq += __shfl_xor(sq, off); sk += __shfl_xor(sk, off); }
  float qs = rsqrtf(sq * (1.f / 128.f) + 1e-6f);
  float ks = rsqrtf(sk * (1.f / 128.f) + 1e-6f);
  q0 *= qs * qw[2 * l]; q1 *= qs * qw[2 * l + 1];
  k0 *= ks * kw[2 * l]; k1 *= ks * kw[2 * l + 1];
  float4 f = *(const float4*)(pe + ((size_t)t * 64 + l) * 4);
  float qo0 = f.x * q0 + f.y * q1, qo1 = f.z * q0 + f.w * q1;
  float ko0 = f.x * k0 + f.y * k1, ko1 = f.z * k0 + f.w * k1;
  size_t o = ((size_t)head * C_L + t) * C_HD + 2 * l;
  *(unsigned*)(qb + o) = (unsigned)f2bf(qo0) | ((unsigned)f2bf(qo1) << 16);
  *(unsigned*)(kb + o) = (unsigned)f2bf(ko0) | ((unsigned)f2bf(ko1) << 16);
  *(unsigned*)(vb + o) = v2;
}

// ---------------- V transpose: [head][t][d] -> [head][d][t] ----------------
__global__ void k_transpose_v(const unsigned short* __restrict__ vb, unsigned short* __restrict__ vT) {
  __shared__ unsigned short tile[32][33];
  int head = blockIdx.z;
  int tbase = blockIdx.x * 32, dbase = blockIdx.y * 32;
  int tx = threadIdx.x & 31, ty = threadIdx.x >> 5;
  const unsigned short* src = vb + (size_t)head * C_L * C_HD;
#pragma unroll
  for (int i = 0; i < 4; ++i)
    tile[ty + i * 8][tx] = src[(size_t)(tbase + ty + i * 8) * C_HD + dbase + tx];
  __syncthreads();
  unsigned short* dst = vT + (size_t)head * C_HD * C_L;
#pragma unroll
  for (int i = 0; i < 4; ++i)
    dst[(size_t)(dbase + ty + i * 8) * C_L + tbase + tx] = tile[tx][ty + i * 8];
}

// ---------------- flash attention ----------------
__global__ __launch_bounds__(256, 2)
void k_attn(const unsigned short* __restrict__ qb, const unsigned short* __restrict__ kb,
            const unsigned short* __restrict__ vT, unsigned short* __restrict__ c2) {
  __shared__ unsigned short P[4][16][32];
  int bid = blockIdx.x;
  int head = bid >> 5, qt = bid & 31;
  int wid = threadIdx.x >> 6, l = threadIdx.x & 63;
  int la = l & 15, lk = l >> 4;
  int q0 = qt * 64 + wid * 16;
  const float sc = 0.08838834764831845f;  // 1/sqrt(128)
  bf16x8 qf[4];
  const unsigned short* qp = qb + ((size_t)head * C_L + q0 + la) * C_HD + lk * 8;
#pragma unroll
  for (int kc = 0; kc < 4; ++kc) qf[kc] = *(const bf16x8*)(qp + kc * 32);
  float m[4] = {-1e30f, -1e30f, -1e30f, -1e30f};
  float ls[4] = {0.f, 0.f, 0.f, 0.f};
  f32x4 o[8] = {};
  const unsigned short* kbp = kb + (size_t)head * C_L * C_HD;
  const unsigned short* vbp = vT + (size_t)head * C_HD * C_L;
  unsigned short* Pw = &P[wid][0][0];

  for (int kv = 0; kv < C_L; kv += 32) {
    f32x4 s0 = {0.f, 0.f, 0.f, 0.f}, s1 = {0.f, 0.f, 0.f, 0.f};
    const unsigned short* kp0 = kbp + (size_t)(kv + la) * C_HD + lk * 8;
    const unsigned short* kp1 = kp0 + 16 * C_HD;
#pragma unroll
    for (int kc = 0; kc < 4; ++kc) {
      s0 = __builtin_amdgcn_mfma_f32_16x16x32_bf16(qf[kc], *(const bf16x8*)(kp0 + kc * 32), s0, 0, 0, 0);
      s1 = __builtin_amdgcn_mfma_f32_16x16x32_bf16(qf[kc], *(const bf16x8*)(kp1 + kc * 32), s1, 0, 0, 0);
    }
    float p0[4], p1[4], corr[4];
#pragma unroll
    for (int j = 0; j < 4; ++j) {
      float a0 = s0[j] * sc, a1 = s1[j] * sc;
      float tm = fmaxf(a0, a1);
      tm = fmaxf(tm, __shfl_xor(tm, 1));
      tm = fmaxf(tm, __shfl_xor(tm, 2));
      tm = fmaxf(tm, __shfl_xor(tm, 4));
      tm = fmaxf(tm, __shfl_xor(tm, 8));
      float mn = fmaxf(m[j], tm);
      corr[j] = __expf(m[j] - mn);
      p0[j] = __expf(a0 - mn);
      p1[j] = __expf(a1 - mn);
      float rsum = p0[j] + p1[j];
      rsum += __shfl_xor(rsum, 1);
      rsum += __shfl_xor(rsum, 2);
      rsum += __shfl_xor(rsum, 4);
      rsum += __shfl_xor(rsum, 8);
      ls[j] = ls[j] * corr[j] + rsum;
      m[j] = mn;
    }
#pragma unroll
    for (int n = 0; n < 8; ++n) {
      o[n][0] *= corr[0]; o[n][1] *= corr[1]; o[n][2] *= corr[2]; o[n][3] *= corr[3];
    }
    // write P[r=q-row][c=kv] swizzled (4 slots/row, XOR r&3)
#pragma unroll
    for (int j = 0; j < 4; ++j) {
      int r = lk * 4 + j;
      {
        int c = la;
        *(unsigned short*)((char*)Pw + r * 64 + (((c >> 3) ^ (r & 3)) * 16) + (c & 7) * 2) = f2bf(p0[j]);
      }
      {
        int c = la + 16;
        *(unsigned short*)((char*)Pw + r * 64 + (((c >> 3) ^ (r & 3)) * 16) + (c & 7) * 2) = f2bf(p1[j]);
      }
    }
    __syncthreads();
    bf16x8 pf = *(const bf16x8*)((char*)Pw + la * 64 + ((lk ^ (la & 3)) * 16));
    const unsigned short* vp = vbp + kv + lk * 8;
#pragma unroll
    for (int n = 0; n < 8; ++n) {
      bf16x8 vf = *(const bf16x8*)(vp + (size_t)(n * 16 + la) * C_L);
      o[n] = __builtin_amdgcn_mfma_f32_16x16x32_bf16(pf, vf, o[n], 0, 0, 0);
    }
    __syncthreads();
  }
#pragma unroll
  for (int n = 0; n < 8; ++n) {
#pragma unroll
    for (int j = 0; j < 4; ++j) {
      int row = q0 + lk * 4 + j;
      int col = head * C_HD + n * 16 + la;
      c2[(size_t)row * C_K2 + col] = f2bf(o[n][j] / ls[j]);
    }
  }
}

// ---------------- gelu(mlp) -> c2[:, 3072:] ----------------
__global__ void k_gelu(const unsigned short* __restrict__ h, unsigned short* __restrict__ c2) {
  int idx = blockIdx.x * 256 + threadIdx.x;   // one us8 per thread, exact cover
  int e = idx * 8;
  int t = e / C_MLP, c = e % C_MLP;
  us8 v = *(const us8*)(h + (size_t)t * C_N1 + 9216 + c);
  us8 o;
#pragma unroll
  for (int i = 0; i < 8; ++i) {
    float x = bf2f(v[i]);
    float g = 0.5f * x * (1.f + tanhf(0.7978845608f * (x + 0.044715f * x * x * x)));
    o[i] = f2bf(g);
  }
  *(us8*)(c2 + (size_t)t * C_K2 + 3072 + c) = o;
}

// ---------------- launch ----------------
extern "C" void kernel_launch(void* const* d_in, const int* in_sizes, int n_in,
                              void* d_out, int out_size, void* d_ws, size_t ws_size,
                              hipStream_t stream) {
  (void)in_sizes; (void)n_in; (void)out_size; (void)ws_size;
  const float* x    = (const float*)d_in[0];
  const float* vec  = (const float*)d_in[1];
  const float* pe   = (const float*)d_in[2];
  const float* w1   = (const float*)d_in[3];
  const float* b1   = (const float*)d_in[4];
  const float* w2   = (const float*)d_in[5];
  const float* b2   = (const float*)d_in[6];
  const float* modw = (const float*)d_in[7];
  const float* modb = (const float*)d_in[8];
  const float* qw   = (const float*)d_in[9];
  const float* kw   = (const float*)d_in[10];
  float* out = (float*)d_out;

  char* ws = (char*)d_ws;
  size_t off = 0;
  auto alloc = [&](size_t bytes) { char* p = ws + off; off += (bytes + 255) & ~(size_t)255; return p; };
  float* partial = (float*)alloc((size_t)16 * 9216 * 4);
  float* modv    = (float*)alloc((size_t)9216 * 4);
  unsigned short* xmod = (unsigned short*)alloc((size_t)C_L * C_HID * 2);
  unsigned short* hbuf = (unsigned short*)alloc((size_t)C_L * C_N1 * 2);
  unsigned short* qbuf = (unsigned short*)alloc((size_t)C_NH * C_L * C_HD * 2);
  unsigned short* kbuf = (unsigned short*)alloc((size_t)C_NH * C_L * C_HD * 2);
  unsigned short* vbuf = (unsigned short*)alloc((size_t)C_NH * C_L * C_HD * 2);
  unsigned short* vTb  = (unsigned short*)alloc((size_t)C_NH * C_L * C_HD * 2);
  unsigned short* c2   = (unsigned short*)alloc((size_t)C_L * C_K2 * 2);

  k_silu_gemv<<<dim3(36, 16), 256, 0, stream>>>(vec, modw, partial);
  k_reduce_mod<<<36, 256, 0, stream>>>(partial, modb, modv);
  k_ln_mod<<<C_L, 256, 0, stream>>>(x, modv, xmod);
  k_gemm<0><<<168 * 16, 256, 0, stream>>>(xmod, w1, b1, hbuf, nullptr, nullptr, nullptr,
                                          C_L, C_N1, C_HID, 16);
  k_qkv_post<<<(C_L * C_NH) / 4, 256, 0, stream>>>(hbuf, pe, qw, kw, qbuf, kbuf, vbuf);
  k_transpose_v<<<dim3(64, 4, 24), 256, 0, stream>>>(vbuf, vTb);
  k_attn<<<24 * 32, 256, 0, stream>>>(qbuf, kbuf, vTb, c2);
  k_gelu<<<(C_L * C_MLP) / (256 * 8), 256, 0, stream>>>(hbuf, c2);
  k_gemm<1><<<24 * 16, 256, 0, stream>>>(c2, w2, b2, nullptr, out, x, modv + 6144,
                                         C_L, C_HID, C_K2, 16);
}